// Round 9
// baseline (91.337 us; speedup 1.0000x reference)
//
#include <hip/hip_runtime.h>
#include <math.h>

typedef __attribute__((ext_vector_type(8))) short bf16x8;
typedef __attribute__((ext_vector_type(4))) short short4v;
typedef __attribute__((ext_vector_type(4))) float f32x4;

#define NB 16
#define NS 720
#define NC 862
#define NP 24
#define NQ 30
#define NDM 128
#define NPRED 336
#define BC (NB*NC)          /* 13792 */
#define SCH 10
#define SLEN 72             /* 720/10 */
#define KP 768              /* padded K: 24 p * 32 q-slots */
#define PBASE (4*BC)        /* stats partials (floats) */
#define WOFF_F (24*BC)      /* float offset of bf16 blobs (16B aligned) */
#define NCOL (NB*NC)        /* fused N dimension of proj GEMM = 13792 */

__device__ __forceinline__ short f2bf(float f) {
    union { float f; unsigned u; } v; v.f = f;
    unsigned r = v.u + 0x7FFFu + ((v.u >> 16) & 1u);   // round-to-nearest-even
    return (short)(r >> 16);
}

// gelu tanh-form: h * sigmoid(2*sqrt(2/pi)*(h + 0.044715 h^3)); |err vs exact| <~2e-4
__device__ __forceinline__ float gelu_f(float h) {
    float hc = fminf(fmaxf(h, -8.f), 8.f);
    float z2 = hc * hc;
    float zz = hc * (0.79788456f + 0.035677408f * z2);   // sqrt(2/pi)*(h+0.044715h^3)
    float e  = __expf(-2.f * zz);
    return h * __builtin_amdgcn_rcpf(1.f + e);
}

// async global->LDS, 16B per lane; LDS dest = wave-uniform base + lane*16
__device__ __forceinline__ void gl_lds16(const void* g, void* l) {
    __builtin_amdgcn_global_load_lds(
        (const __attribute__((address_space(1))) unsigned int*)g,
        (__attribute__((address_space(3))) unsigned int*)l, 16, 0, 0);
}

// ---------------- stats: two-phase, deterministic ----------------
__global__ __launch_bounds__(256) void stats_partial_k(const float* __restrict__ x,
                                                       float* __restrict__ ws) {
    int b = blockIdx.x, half = blockIdx.y, ch = blockIdx.z;
    int t = half * 256 + threadIdx.x;
    if (t >= NC / 2) return;                 // 431 float2 per row (862 = 2*431)
    const float2* xp = (const float2*)(x + ((size_t)b * NS + (size_t)ch * SLEN) * NC) + t;
    float2 s = {0.f, 0.f}, sq = {0.f, 0.f};
    #pragma unroll 4
    for (int i = 0; i < SLEN; ++i) {
        float2 v = xp[(size_t)i * (NC / 2)];
        s.x += v.x; s.y += v.y;
        sq.x += v.x * v.x; sq.y += v.y * v.y;
    }
    int idx = b * NC + t * 2;
    float* ps = ws + PBASE;
    *(float2*)&ps[(size_t)ch * BC + idx] = s;
    *(float2*)&ps[(size_t)(SCH + ch) * BC + idx] = sq;
}

__global__ __launch_bounds__(256) void stats_final_k(float* __restrict__ ws,
                                                     const float* __restrict__ revw,
                                                     const float* __restrict__ revb) {
    int idx = blockIdx.x * 256 + threadIdx.x;
    if (idx >= BC) return;
    const float* ps = ws + PBASE;
    float s = 0.f, sq = 0.f;
    #pragma unroll
    for (int ch = 0; ch < SCH; ++ch) {
        s  += ps[(size_t)ch * BC + idx];
        sq += ps[(size_t)(SCH + ch) * BC + idx];
    }
    int c = idx % NC;
    float mean  = s * (1.f / NS);
    float var   = sq * (1.f / NS) - mean * mean;
    float stdev = sqrtf(var + 1e-5f);
    float rstd  = 1.f / stdev;
    float aw = revw[c] * rstd;
    float u  = stdev / (revw[c] + 1e-10f);
    ws[idx]          = aw;                     // AW
    ws[BC + idx]     = revb[c] - mean * aw;    // BW
    ws[2 * BC + idx] = u;                      // U
    ws[3 * BC + idx] = mean - revb[c] * u;     // V
}

// ---------------- prep: frag-major bf16 weight blobs (direct global MFMA frags) ------
__global__ __launch_bounds__(256) void wprep_k(const float* __restrict__ W1,
                                               const float* __restrict__ W2,
                                               unsigned short* __restrict__ W1FF,
                                               unsigned short* __restrict__ W2FF) {
    int p = blockIdx.x, tid = threadIdx.x;
    const float* w1 = W1 + (size_t)(NP + p) * NDM * NQ;   // layer 1 only
    const float* w2 = W2 + (size_t)(NP + p) * NQ * NDM;
    #pragma unroll
    for (int pass = 0; pass < 2; ++pass) {
        int s = pass * 256 + tid;                  // 512 frag-lanes per blob
        int l = s & 63, lr = l & 15, lg = l >> 4;
        {   // W1FF[dt][l]: A of H-GEMM, rows=d(dt*16+lr), k=q(8lg+j), dt in [0,8)
            int dt = s >> 6;
            int d = dt * 16 + lr;
            bf16x8 v;
            #pragma unroll
            for (int j = 0; j < 8; ++j) {
                int q = 8 * lg + j;
                v[j] = f2bf(q < NQ ? w1[d * NQ + q] : 0.f);
            }
            ((bf16x8*)(W1FF + (size_t)p * 4096))[s] = v;
        }
        {   // W2FF[mi*4+ks][l]: A of Y-GEMM, rows=q(mi*16+lr), k=d(ks*32+8lg+j)
            int g = s >> 6, mi = g >> 2, ks = g & 3;
            int q = mi * 16 + lr, k = ks * 32 + 8 * lg;
            bf16x8 v;
            #pragma unroll
            for (int j = 0; j < 8; ++j)
                v[j] = f2bf(q < NQ ? w2[q * NDM + k + j] : 0.f);
            ((bf16x8*)(W2FF + (size_t)p * 4096))[s] = v;
        }
    }
}

// PWPF[st][ks][l][j] = pw[m=st*16+lr][k: q=8lg+j, p=ks] (zeros m>=336 or q>=30)
__global__ __launch_bounds__(256) void pwprep_k(const float* __restrict__ pw,
                                                unsigned short* __restrict__ PWPF) {
    int t = blockIdx.x * 256 + threadIdx.x;
    if (t >= 24 * 24 * 64) return;
    int l = t & 63, ks = (t >> 6) % 24, st = t / (24 * 64);
    int lr = l & 15, lg = l >> 4;
    int m = st * 16 + lr;
    bf16x8 v;
    #pragma unroll
    for (int j = 0; j < 8; ++j) {
        int q = 8 * lg + j;
        v[j] = f2bf((m < NPRED && q < NQ) ? pw[(size_t)m * NS + q * NP + ks] : 0.f);
    }
    ((bf16x8*)PWPF)[t] = v;
}

// ---------------- branch v7: p-loop pipelined, 6 p per block ----------------
// Grid 14 x 4 x 16 = 896 blocks. Double-buffered XsB; next-p x loads + this-iter W2
// frags issued right after the top barrier (latency hides under H-MFMA + gelu; the
// mid-barrier vmcnt drain lands them exactly when consumed). aw/bw hoisted per block.
__global__ __launch_bounds__(256, 3) void branch_k(const float* __restrict__ x,
        const unsigned short* __restrict__ W1FF, const unsigned short* __restrict__ W2FF,
        const float* __restrict__ ws, unsigned short* __restrict__ y_t) {
    __shared__ __align__(16) short XsB[2][4 * 64 * 8];   // 2 x 4KB
    __shared__ __align__(16) short HB [16 * 64 * 8];     // 16KB
    int tid = threadIdx.x;
    int c0 = blockIdx.x * 64;
    int pg = blockIdx.y * 6;           // first p of this block's group
    int b  = blockIdx.z;

    // staging role
    int cS = tid & 63, kbS = tid >> 6;
    int cgS = c0 + cS;
    bool cv = cgS < NC;
    int ce = cv ? cgS : NC - 1;
    float aw = ws[b * NC + ce];
    float bw = ws[BC + b * NC + ce];
    const float* xb = x + (size_t)b * NS * NC + ce;

    // compute role
    int w = tid >> 6, l = tid & 63, lr = l & 15, lg = l >> 4;
    f32x4 zf = {0.f, 0.f, 0.f, 0.f};

    {   // prologue: stage Xs for p = pg
        bf16x8 v;
        #pragma unroll
        for (int j = 0; j < 8; ++j) {
            int q = kbS * 8 + j;
            float val = (q < NQ && cv) ? xb[(size_t)(q * NP + pg) * NC] * aw + bw : 0.f;
            v[j] = f2bf(val);
        }
        *(bf16x8*)&XsB[0][(size_t)(kbS * 64 + (cS ^ kbS)) * 8] = v;
    }

    int cg2 = c0 + w * 16 + lr;
    for (int pp = 0; pp < 6; ++pp) {
        int p = pg + pp;
        const bf16x8* w1p = (const bf16x8*)(W1FF + (size_t)p * 4096);
        const bf16x8* w2p = (const bf16x8*)(W2FF + (size_t)p * 4096);
        __syncthreads();                 // XsB[pp&1] visible; HB free (prev Y reads done)

        // prefetch next-p x (consumed after mid barrier, converted at iter bottom)
        float xn[8];
        if (pp < 5) {
            #pragma unroll
            for (int j = 0; j < 8; ++j) {
                int q = kbS * 8 + j;
                xn[j] = (q < NQ && cv) ? xb[(size_t)(q * NP + p + 1) * NC] * aw + bw : 0.f;
            }
        }
        // prefetch this-iter W2 frags (consumed in Y phase, after mid barrier)
        bf16x8 w2f[8];
        #pragma unroll
        for (int g = 0; g < 8; ++g) w2f[g] = w2p[g * 64 + l];

        // H = W1 @ Xs : M=128(d), N=64(c), K=32
        bf16x8 a0 = w1p[(2 * w) * 64 + l];
        bf16x8 a1 = w1p[(2 * w + 1) * 64 + l];
        f32x4 hc[2][4];
        #pragma unroll
        for (int ni = 0; ni < 4; ++ni) {
            bf16x8 bfr = *(const bf16x8*)&XsB[pp & 1]
                             [(size_t)(lg * 64 + ((ni * 16 + lr) ^ lg)) * 8];
            hc[0][ni] = __builtin_amdgcn_mfma_f32_16x16x32_bf16(a0, bfr, zf, 0, 0, 0);
            hc[1][ni] = __builtin_amdgcn_mfma_f32_16x16x32_bf16(a1, bfr, zf, 0, 0, 0);
        }
        // gelu + write H^T into HB (rows=c, K=d), XOR swizzle
        #pragma unroll
        for (int mi2 = 0; mi2 < 2; ++mi2) {
            int d0 = (2 * w + mi2) * 16 + 4 * lg;
            int kb = d0 >> 3, sub = d0 & 7;
            #pragma unroll
            for (int ni = 0; ni < 4; ++ni) {
                short4v v;
                #pragma unroll
                for (int r = 0; r < 4; ++r)
                    v[r] = f2bf(gelu_f(hc[mi2][ni][r]));
                int col = ni * 16 + lr;
                *(short4v*)&HB[(size_t)(kb * 64 + (col ^ kb)) * 8 + sub] = v;
            }
        }
        __syncthreads();                 // HB ready; xn/w2f landed (drain)

        // Y = W2 @ H : M=32(q), N=64(c), K=128
        f32x4 yacc[2] = {zf, zf};
        #pragma unroll
        for (int ks = 0; ks < 4; ++ks) {
            int kb = ks * 4 + lg;
            bf16x8 hfr = *(const bf16x8*)&HB[(size_t)(kb * 64 + ((w * 16 + lr) ^ kb)) * 8];
            #pragma unroll
            for (int mi = 0; mi < 2; ++mi)
                yacc[mi] = __builtin_amdgcn_mfma_f32_16x16x32_bf16(w2f[mi * 4 + ks], hfr,
                                                                  yacc[mi], 0, 0, 0);
        }
        if (cg2 < NC) {
            unsigned short* base = y_t + ((size_t)(b * NC + cg2)) * KP + p * 32;
            #pragma unroll
            for (int mi = 0; mi < 2; ++mi) {
                int q0 = mi * 16 + 4 * lg;
                short4v v;
                #pragma unroll
                for (int r = 0; r < 4; ++r)
                    v[r] = (q0 + r < NQ) ? f2bf(yacc[mi][r]) : (short)0;
                *(short4v*)(base + q0) = v;
            }
        }
        // convert + write next Xs (buffer last read 2 barriers ago -> safe)
        if (pp < 5) {
            bf16x8 v;
            #pragma unroll
            for (int j = 0; j < 8; ++j) v[j] = f2bf(xn[j]);
            *(bf16x8*)&XsB[(pp + 1) & 1][(size_t)(kbS * 64 + (cS ^ kbS)) * 8] = v;
        }
    }
}

// ---------------- projection v6: counted-vmcnt pipeline (T3/T4-lite) -----------------
// 64x128 tile, 648 blocks, 3 LDS buffers (36KB), stage-ahead-2.
// Per iter: s_waitcnt vmcnt(3) (oldest stage landed, next stays in flight) + s_barrier,
// compute, then stage ks+2. vmcnt(0) only on the last iter. WAR-safe: write target was
// last read one barrier ago; reads complete before the barrier (ds_read->MFMA dep);
// wait-before-barrier gives cross-wave visibility.
__global__ __launch_bounds__(256, 3) void proj_k(const unsigned short* __restrict__ PWPF,
        const float* __restrict__ pb, const float* __restrict__ ws,
        const unsigned short* __restrict__ y_t, float* __restrict__ out) {
    __shared__ __align__(16) short L[3][12 * 512];   // slots 0..3 = A(st), 4..11 = B
    int tid = threadIdx.x;
    int w = tid >> 6, l = tid & 63, lr = l & 15, lg = l >> 4;
    int n0 = blockIdx.x * 128, m0 = blockIdx.y * 64;
    f32x4 zf = {0.f, 0.f, 0.f, 0.f};
    f32x4 acc[4][2];
    #pragma unroll
    for (int mi = 0; mi < 4; ++mi) { acc[mi][0] = zf; acc[mi][1] = zf; }

    int cB0 = n0 + (2 * w) * 16 + lr;      if (cB0 > NCOL - 1) cB0 = NCOL - 1;
    int cB1 = n0 + (2 * w + 1) * 16 + lr;  if (cB1 > NCOL - 1) cB1 = NCOL - 1;
    const unsigned short* sA  = PWPF + ((size_t)(m0 / 16 + w) * 24) * 512 + (size_t)l * 8;
    const unsigned short* sB0 = y_t + (size_t)cB0 * KP + lg * 8;
    const unsigned short* sB1 = y_t + (size_t)cB1 * KP + lg * 8;

#define STAGE(BUF, KS) do {                                          \
        gl_lds16(sA  + (size_t)(KS) * 512, &L[BUF][w * 512]);        \
        gl_lds16(sB0 + (size_t)(KS) * 32,  &L[BUF][(4 + 2 * w) * 512]); \
        gl_lds16(sB1 + (size_t)(KS) * 32,  &L[BUF][(5 + 2 * w) * 512]); } while (0)

    STAGE(0, 0);
    STAGE(1, 1);
    #pragma unroll
    for (int ks = 0; ks < 24; ++ks) {
        if (ks < 23) asm volatile("s_waitcnt vmcnt(3)\n\ts_barrier" ::: "memory");
        else         asm volatile("s_waitcnt vmcnt(0)\n\ts_barrier" ::: "memory");
        const short* Lc = L[ks % 3];
        bf16x8 b0 = *(const bf16x8*)&Lc[(4 + 2 * w) * 512 + l * 8];
        bf16x8 b1 = *(const bf16x8*)&Lc[(5 + 2 * w) * 512 + l * 8];
        #pragma unroll
        for (int mi = 0; mi < 4; ++mi) {
            bf16x8 a = *(const bf16x8*)&Lc[mi * 512 + l * 8];
            acc[mi][0] = __builtin_amdgcn_mfma_f32_16x16x32_bf16(a, b0, acc[mi][0], 0, 0, 0);
            acc[mi][1] = __builtin_amdgcn_mfma_f32_16x16x32_bf16(a, b1, acc[mi][1], 0, 0, 0);
        }
        if (ks + 2 < 24) STAGE((ks + 2) % 3, ks + 2);
    }
#undef STAGE

    #pragma unroll
    for (int mi = 0; mi < 4; ++mi) {
        #pragma unroll
        for (int r = 0; r < 4; ++r) {
            int pr = m0 + mi * 16 + 4 * lg + r;
            if (pr >= NPRED) continue;           // M padded to 384
            float bias = pb[pr];
            #pragma unroll
            for (int nj = 0; nj < 2; ++nj) {
                int cg = n0 + (2 * w + nj) * 16 + lr;
                if (cg >= NCOL) continue;
                int bb = cg / NC;
                int cc = cg - bb * NC;
                out[((size_t)bb * NPRED + pr) * NC + cc] =
                    (acc[mi][nj][r] + bias) * ws[2 * BC + cg] + ws[3 * BC + cg];
            }
        }
    }
}

extern "C" void kernel_launch(void* const* d_in, const int* in_sizes, int n_in,
                              void* d_out, int out_size, void* d_ws, size_t ws_size,
                              hipStream_t stream) {
    const float* x   = (const float*)d_in[0];
    const float* W1  = (const float*)d_in[1];
    const float* W2  = (const float*)d_in[2];
    const float* pw  = (const float*)d_in[3];
    const float* pb  = (const float*)d_in[4];
    const float* rw  = (const float*)d_in[5];
    const float* rb  = (const float*)d_in[6];
    float* out = (float*)d_out;
    float* ws  = (float*)d_ws;
    unsigned short* W1FF = (unsigned short*)(ws + WOFF_F);
    unsigned short* W2FF = W1FF + NP * 4096;
    unsigned short* PWPF = W2FF + NP * 4096;
    unsigned short* y_t  = PWPF + 24 * 24 * 64 * 8;

    stats_partial_k<<<dim3(NB, 2, SCH), 256, 0, stream>>>(x, ws);
    wprep_k<<<dim3(NP), 256, 0, stream>>>(W1, W2, W1FF, W2FF);
    pwprep_k<<<dim3((24 * 24 * 64 + 255) / 256), 256, 0, stream>>>(pw, PWPF);
    stats_final_k<<<dim3((BC + 255) / 256), 256, 0, stream>>>(ws, rw, rb);
    branch_k<<<dim3(14, 4, NB), 256, 0, stream>>>(x, W1FF, W2FF, ws, y_t);
    proj_k<<<dim3((NCOL + 127) / 128, 6), 256, 0, stream>>>(PWPF, pb, ws, y_t, out);
}

// Round 10
// 85.610 us; speedup vs baseline: 1.0669x; 1.0669x over previous
//
#include <hip/hip_runtime.h>
#include <math.h>

typedef __attribute__((ext_vector_type(8))) short bf16x8;
typedef __attribute__((ext_vector_type(4))) short short4v;
typedef __attribute__((ext_vector_type(4))) float f32x4;

#define NB 16
#define NS 720
#define NC 862
#define NP 24
#define NQ 30
#define NDM 128
#define NPRED 336
#define BC (NB*NC)          /* 13792 */
#define SCH 10
#define SLEN 72             /* 720/10 */
#define KP 768              /* padded K: 24 p * 32 q-slots */
#define PBASE (4*BC)        /* stats partials (floats) */
#define WOFF_F (24*BC)      /* float offset of bf16 blobs (16B aligned) */
#define NCOL (NB*NC)        /* fused N dimension of proj GEMM = 13792 */

__device__ __forceinline__ short f2bf(float f) {
    union { float f; unsigned u; } v; v.f = f;
    unsigned r = v.u + 0x7FFFu + ((v.u >> 16) & 1u);   // round-to-nearest-even
    return (short)(r >> 16);
}

// packed f32x2 -> bf16x2 in one VALU op (dst low16 = a, high16 = b)
__device__ __forceinline__ unsigned cvt_pk_bf16(float a, float b) {
    unsigned r;
    asm("v_cvt_pk_bf16_f32 %0, %1, %2" : "=v"(r) : "v"(a), "v"(b));
    return r;
}

// gelu tanh-form, no clamp (exp saturates safely: h<<0 -> e=inf -> rcp=0 -> 0;
// h>>0 -> e=0 -> h). |err vs exact| <~2e-4.
__device__ __forceinline__ float gelu_f(float h) {
    float z2 = h * h;
    float zz = h * (0.79788456f + 0.035677408f * z2);   // sqrt(2/pi)*(h+0.044715h^3)
    float e  = __expf(-2.f * zz);
    return h * __builtin_amdgcn_rcpf(1.f + e);
}

// async global->LDS, 16B per lane; LDS dest = wave-uniform base + lane*16
__device__ __forceinline__ void gl_lds16(const void* g, void* l) {
    __builtin_amdgcn_global_load_lds(
        (const __attribute__((address_space(1))) unsigned int*)g,
        (__attribute__((address_space(3))) unsigned int*)l, 16, 0, 0);
}

// ---------------- stats: two-phase, deterministic ----------------
__global__ __launch_bounds__(256) void stats_partial_k(const float* __restrict__ x,
                                                       float* __restrict__ ws) {
    int b = blockIdx.x, half = blockIdx.y, ch = blockIdx.z;
    int t = half * 256 + threadIdx.x;
    if (t >= NC / 2) return;                 // 431 float2 per row (862 = 2*431)
    const float2* xp = (const float2*)(x + ((size_t)b * NS + (size_t)ch * SLEN) * NC) + t;
    float2 s = {0.f, 0.f}, sq = {0.f, 0.f};
    #pragma unroll 4
    for (int i = 0; i < SLEN; ++i) {
        float2 v = xp[(size_t)i * (NC / 2)];
        s.x += v.x; s.y += v.y;
        sq.x += v.x * v.x; sq.y += v.y * v.y;
    }
    int idx = b * NC + t * 2;
    float* ps = ws + PBASE;
    *(float2*)&ps[(size_t)ch * BC + idx] = s;
    *(float2*)&ps[(size_t)(SCH + ch) * BC + idx] = sq;
}

__global__ __launch_bounds__(256) void stats_final_k(float* __restrict__ ws,
                                                     const float* __restrict__ revw,
                                                     const float* __restrict__ revb) {
    int idx = blockIdx.x * 256 + threadIdx.x;
    if (idx >= BC) return;
    const float* ps = ws + PBASE;
    float s = 0.f, sq = 0.f;
    #pragma unroll
    for (int ch = 0; ch < SCH; ++ch) {
        s  += ps[(size_t)ch * BC + idx];
        sq += ps[(size_t)(SCH + ch) * BC + idx];
    }
    int c = idx % NC;
    float mean  = s * (1.f / NS);
    float var   = sq * (1.f / NS) - mean * mean;
    float stdev = sqrtf(var + 1e-5f);
    float rstd  = 1.f / stdev;
    float aw = revw[c] * rstd;
    float u  = stdev / (revw[c] + 1e-10f);
    ws[idx]          = aw;                     // AW
    ws[BC + idx]     = revb[c] - mean * aw;    // BW
    ws[2 * BC + idx] = u;                      // U
    ws[3 * BC + idx] = mean - revb[c] * u;     // V
}

// ---------------- prep: frag-major bf16 weight blobs (direct global MFMA frags) ------
__global__ __launch_bounds__(256) void wprep_k(const float* __restrict__ W1,
                                               const float* __restrict__ W2,
                                               unsigned short* __restrict__ W1FF,
                                               unsigned short* __restrict__ W2FF) {
    int p = blockIdx.x, tid = threadIdx.x;
    const float* w1 = W1 + (size_t)(NP + p) * NDM * NQ;   // layer 1 only
    const float* w2 = W2 + (size_t)(NP + p) * NQ * NDM;
    #pragma unroll
    for (int pass = 0; pass < 2; ++pass) {
        int s = pass * 256 + tid;                  // 512 frag-lanes per blob
        int l = s & 63, lr = l & 15, lg = l >> 4;
        {   // W1FF[dt][l]: A of H-GEMM, rows=d(dt*16+lr), k=q(8lg+j), dt in [0,8)
            int dt = s >> 6;
            int d = dt * 16 + lr;
            bf16x8 v;
            #pragma unroll
            for (int j = 0; j < 8; ++j) {
                int q = 8 * lg + j;
                v[j] = f2bf(q < NQ ? w1[d * NQ + q] : 0.f);
            }
            ((bf16x8*)(W1FF + (size_t)p * 4096))[s] = v;
        }
        {   // W2FF[mi*4+ks][l]: A of Y-GEMM, rows=q(mi*16+lr), k=d(ks*32+8lg+j)
            int g = s >> 6, mi = g >> 2, ks = g & 3;
            int q = mi * 16 + lr, k = ks * 32 + 8 * lg;
            bf16x8 v;
            #pragma unroll
            for (int j = 0; j < 8; ++j)
                v[j] = f2bf(q < NQ ? w2[q * NDM + k + j] : 0.f);
            ((bf16x8*)(W2FF + (size_t)p * 4096))[s] = v;
        }
    }
}

// PWPF[st][ks][l][j] = pw[m=st*16+lr][k: q=8lg+j, p=ks] (zeros m>=336 or q>=30)
__global__ __launch_bounds__(256) void pwprep_k(const float* __restrict__ pw,
                                                unsigned short* __restrict__ PWPF) {
    int t = blockIdx.x * 256 + threadIdx.x;
    if (t >= 24 * 24 * 64) return;
    int l = t & 63, ks = (t >> 6) % 24, st = t / (24 * 64);
    int lr = l & 15, lg = l >> 4;
    int m = st * 16 + lr;
    bf16x8 v;
    #pragma unroll
    for (int j = 0; j < 8; ++j) {
        int q = 8 * lg + j;
        v[j] = f2bf((m < NPRED && q < NQ) ? pw[(size_t)m * NS + q * NP + ks] : 0.f);
    }
    ((bf16x8*)PWPF)[t] = v;
}

// ---------------- branch v8: 512 thr, 128-c tile, 1 p/block, cvt_pk conversions ------
// Grid 7 x 24 x 16 = 2688 blocks, 8 waves. H: wave w = d-tile w over 8 c-tiles (8 MFMA);
// Y: wave w = c-tile w, 2 q-tiles x 4 ks (8 MFMA). LDS 40KB -> with (512,4) ~16
// waves/CU (2 blocks): 2x the occupancy of r9's 26%.
__global__ __launch_bounds__(512, 4) void branch_k(const float* __restrict__ x,
        const unsigned short* __restrict__ W1FF, const unsigned short* __restrict__ W2FF,
        const float* __restrict__ ws, unsigned short* __restrict__ y_t) {
    __shared__ __align__(16) short XsB[4 * 128 * 8];    // 8KB : rows=c(128), K=q(32)
    __shared__ __align__(16) short HB [16 * 128 * 8];   // 32KB: rows=c(128), K=d(128)
    int tid = threadIdx.x;
    int c0 = blockIdx.x * 128;
    int p  = blockIdx.y;
    int b  = blockIdx.z;

    {   // stage Xs: thread -> (c = tid&127, kb = tid>>7), one bf16x8 via 4 cvt_pk
        int cS = tid & 127, kbS = tid >> 7;
        int cgS = c0 + cS;
        bool cv = cgS < NC;
        int ce = cv ? cgS : NC - 1;
        float aw = ws[b * NC + ce];
        float bw = ws[BC + b * NC + ce];
        const float* xb = x + ((size_t)b * NS + p) * NC + ce;
        float xs[8];
        #pragma unroll
        for (int j = 0; j < 8; ++j) {
            int q = kbS * 8 + j;
            xs[j] = (q < NQ && cv) ? xb[(size_t)q * NP * NC] * aw + bw : 0.f;
        }
        unsigned u[4];
        #pragma unroll
        for (int i = 0; i < 4; ++i) u[i] = cvt_pk_bf16(xs[2 * i], xs[2 * i + 1]);
        *(uint4*)&XsB[(size_t)(kbS * 128 + (cS ^ kbS)) * 8] = *(uint4*)u;
    }

    int w = tid >> 6, l = tid & 63, lr = l & 15, lg = l >> 4;
    f32x4 zf = {0.f, 0.f, 0.f, 0.f};
    const bf16x8* w1p = (const bf16x8*)(W1FF + (size_t)p * 4096);
    const bf16x8* w2p = (const bf16x8*)(W2FF + (size_t)p * 4096);
    bf16x8 a0 = w1p[w * 64 + l];          // wave w's d-tile A-frag (L2-hot)
    bf16x8 w2f[8];
    #pragma unroll
    for (int g = 0; g < 8; ++g) w2f[g] = w2p[g * 64 + l];

    __syncthreads();

    // H = W1 @ Xs : M=128(d), N=128(c), K=32. Wave w owns d-tile w, all 8 c-tiles.
    f32x4 hc[8];
    #pragma unroll
    for (int ni = 0; ni < 8; ++ni) {
        bf16x8 bfr = *(const bf16x8*)&XsB[(size_t)(lg * 128 + ((ni * 16 + lr) ^ lg)) * 8];
        hc[ni] = __builtin_amdgcn_mfma_f32_16x16x32_bf16(a0, bfr, zf, 0, 0, 0);
    }
    // gelu + write H^T into HB (rows=c, K=d), XOR swizzle, 2 cvt_pk per c-tile
    {
        int d0 = w * 16 + 4 * lg;
        int kb = d0 >> 3, sub = d0 & 7;            // sub in {0,4}
        #pragma unroll
        for (int ni = 0; ni < 8; ++ni) {
            unsigned u0 = cvt_pk_bf16(gelu_f(hc[ni][0]), gelu_f(hc[ni][1]));
            unsigned u1 = cvt_pk_bf16(gelu_f(hc[ni][2]), gelu_f(hc[ni][3]));
            int col = ni * 16 + lr;
            unsigned* dst = (unsigned*)&HB[(size_t)(kb * 128 + (col ^ kb)) * 8 + sub];
            dst[0] = u0; dst[1] = u1;
        }
    }
    __syncthreads();

    // Y = W2 @ H : M=32(q), N=128(c), K=128. Wave w owns c-tile w.
    f32x4 yacc[2] = {zf, zf};
    #pragma unroll
    for (int ks = 0; ks < 4; ++ks) {
        int kb = ks * 4 + lg;
        bf16x8 hfr = *(const bf16x8*)&HB[(size_t)(kb * 128 + ((w * 16 + lr) ^ kb)) * 8];
        #pragma unroll
        for (int mi = 0; mi < 2; ++mi)
            yacc[mi] = __builtin_amdgcn_mfma_f32_16x16x32_bf16(w2f[mi * 4 + ks], hfr,
                                                              yacc[mi], 0, 0, 0);
    }
    // store: c = c0 + w*16+lr; q = mi*16+4lg+r -> one 8B store per mi.
    // q0=28 pair (30,31) zeroed (y_t K-pad must stay zero for proj).
    int cg2 = c0 + w * 16 + lr;
    if (cg2 < NC) {
        unsigned short* base = y_t + ((size_t)(b * NC + cg2)) * KP + p * 32;
        #pragma unroll
        for (int mi = 0; mi < 2; ++mi) {
            int q0 = mi * 16 + 4 * lg;
            unsigned u0 = cvt_pk_bf16(yacc[mi][0], yacc[mi][1]);
            unsigned u1 = (q0 + 2 < NQ) ? cvt_pk_bf16(yacc[mi][2], yacc[mi][3]) : 0u;
            uint2 uv = make_uint2(u0, u1);
            *(uint2*)(base + q0) = uv;
        }
    }
}

// ---------------- projection (r6 form, best known ~32us): fused GEMM 384x13792x768 ---
// 64x128 tile, 4 waves, global_load_lds staging, 2-buffer LDS, 1 barrier per K-step.
__global__ __launch_bounds__(256, 4) void proj_k(const unsigned short* __restrict__ PWPF,
        const float* __restrict__ pb, const float* __restrict__ ws,
        const unsigned short* __restrict__ y_t, float* __restrict__ out) {
    __shared__ __align__(16) short L[2][12 * 512];   // slots 0..3 = A(st), 4..11 = B
    int tid = threadIdx.x;
    int w = tid >> 6, l = tid & 63, lr = l & 15, lg = l >> 4;
    int gn0 = blockIdx.x * 128;          // fused col base (n = b*NC + c)
    int m0  = blockIdx.y * 64;           // pr base
    f32x4 zf = {0.f, 0.f, 0.f, 0.f};
    f32x4 acc[4][2];
    #pragma unroll
    for (int mi = 0; mi < 4; ++mi) { acc[mi][0] = zf; acc[mi][1] = zf; }

    int cgA = gn0 + (2 * w) * 16 + lr;      if (cgA > NCOL - 1) cgA = NCOL - 1;
    int cgB = gn0 + (2 * w + 1) * 16 + lr;  if (cgB > NCOL - 1) cgB = NCOL - 1;
    const unsigned short* bsrcA = y_t + (size_t)cgA * KP + lg * 8;
    const unsigned short* bsrcB = y_t + (size_t)cgB * KP + lg * 8;
    const unsigned short* asrc  = PWPF + ((size_t)(m0 / 16 + w) * 24) * 512 + (size_t)l * 8;

#define STAGE(BUF, KS) do {                                              \
        gl_lds16(asrc  + (size_t)(KS) * 512, &L[BUF][w * 512]);          \
        gl_lds16(bsrcA + (size_t)(KS) * 32,  &L[BUF][(4 + 2 * w) * 512]);\
        gl_lds16(bsrcB + (size_t)(KS) * 32,  &L[BUF][(5 + 2 * w) * 512]);\
    } while (0)

    STAGE(0, 0);
    __syncthreads();
    int cur = 0;
    for (int ks = 0; ks < 24; ++ks) {
        if (ks + 1 < 24) STAGE(cur ^ 1, ks + 1);
        const short* Lc = L[cur];
        bf16x8 b0 = *(const bf16x8*)&Lc[(4 + 2 * w) * 512 + l * 8];
        bf16x8 b1 = *(const bf16x8*)&Lc[(5 + 2 * w) * 512 + l * 8];
        #pragma unroll
        for (int mi = 0; mi < 4; ++mi) {
            bf16x8 a = *(const bf16x8*)&Lc[mi * 512 + l * 8];
            acc[mi][0] = __builtin_amdgcn_mfma_f32_16x16x32_bf16(a, b0, acc[mi][0], 0, 0, 0);
            acc[mi][1] = __builtin_amdgcn_mfma_f32_16x16x32_bf16(a, b1, acc[mi][1], 0, 0, 0);
        }
        __syncthreads();
        cur ^= 1;
    }
#undef STAGE

    #pragma unroll
    for (int mi = 0; mi < 4; ++mi) {
        #pragma unroll
        for (int r = 0; r < 4; ++r) {
            int pr = m0 + mi * 16 + 4 * lg + r;
            if (pr >= NPRED) continue;
            float bias = pb[pr];
            #pragma unroll
            for (int nj = 0; nj < 2; ++nj) {
                int cg = gn0 + (2 * w + nj) * 16 + lr;
                if (cg >= NCOL) continue;
                int bb = cg / NC;
                int cc = cg - bb * NC;
                out[((size_t)bb * NPRED + pr) * NC + cc] =
                    (acc[mi][nj][r] + bias) * ws[2 * BC + cg] + ws[3 * BC + cg];
            }
        }
    }
}

extern "C" void kernel_launch(void* const* d_in, const int* in_sizes, int n_in,
                              void* d_out, int out_size, void* d_ws, size_t ws_size,
                              hipStream_t stream) {
    const float* x   = (const float*)d_in[0];
    const float* W1  = (const float*)d_in[1];
    const float* W2  = (const float*)d_in[2];
    const float* pw  = (const float*)d_in[3];
    const float* pb  = (const float*)d_in[4];
    const float* rw  = (const float*)d_in[5];
    const float* rb  = (const float*)d_in[6];
    float* out = (float*)d_out;
    float* ws  = (float*)d_ws;
    unsigned short* W1FF = (unsigned short*)(ws + WOFF_F);
    unsigned short* W2FF = W1FF + NP * 4096;
    unsigned short* PWPF = W2FF + NP * 4096;
    unsigned short* y_t  = PWPF + 24 * 24 * 64 * 8;

    stats_partial_k<<<dim3(NB, 2, SCH), 256, 0, stream>>>(x, ws);
    wprep_k<<<dim3(NP), 256, 0, stream>>>(W1, W2, W1FF, W2FF);
    pwprep_k<<<dim3((24 * 24 * 64 + 255) / 256), 256, 0, stream>>>(pw, PWPF);
    stats_final_k<<<dim3((BC + 255) / 256), 256, 0, stream>>>(ws, rw, rb);
    branch_k<<<dim3(7, NP, NB), 512, 0, stream>>>(x, W1FF, W2FF, ws, y_t);
    proj_k<<<dim3((NCOL + 127) / 128, 6), 256, 0, stream>>>(PWPF, pb, ws, y_t, out);
}